// Round 15
// baseline (429.062 us; speedup 1.0000x reference)
//
#include <hip/hip_runtime.h>
#include <hip/hip_bf16.h>

typedef __attribute__((ext_vector_type(8))) short s16x8;   // 8 bf16 (4 VGPRs)
typedef __attribute__((ext_vector_type(4))) float f32x4;
typedef unsigned short u16;
typedef unsigned int u32;

#define SDIM 2048
#define BDIM 2
#define HDIM 12
#define DDIM 64
#define EDIM 768
#define MDIM 4096          // S*B rows
#define SCALE_Q 0.125f     // D^-0.5
#define KSPLIT 1024        // keys per wave (2 waves split the 2048-key range)
#define NIT (KSPLIT / 32)  // 32 bodies per wave
#define HFRAG 131072       // per-head fragment-tensor elements (2048*64)

static __device__ __forceinline__ f32x4 zero4() {
    f32x4 v; v[0] = v[1] = v[2] = v[3] = 0.f; return v;
}

// fp32 -> bf16 bits, round-to-nearest-even
static __device__ __forceinline__ u16 f2b(float x) {
    u32 u = __builtin_bit_cast(u32, x);
    u32 lsb = (u >> 16) & 1u;
    u += 0x7fffu + lsb;
    return (u16)(u >> 16);
}

// pack two f32 -> one u32 of 2x bf16 (RNE) via HW instruction
static __device__ __forceinline__ u32 cvt_pk_bf16(float lo, float hi) {
    u32 r;
    asm("v_cvt_pk_bf16_f32 %0, %1, %2" : "=v"(r) : "v"(lo), "v"(hi));
    return r;
}

static __device__ __forceinline__ f32x4 mfma16(s16x8 a, s16x8 b, f32x4 c) {
    return __builtin_amdgcn_mfma_f32_16x16x32_bf16(a, b, c, 0, 0, 0);
}

// async global -> LDS, 16B per lane. LDS dest = wave-uniform base + lane*16.
static __device__ __forceinline__ void gload_lds16(const void* g, void* l) {
    __builtin_amdgcn_global_load_lds(
        (const __attribute__((address_space(1))) void*)g,
        (__attribute__((address_space(3))) void*)l, 16, 0, 0);
}

// ---------------------------------------------------------------------------
// mask -> bitmask (128 u32; bit k = key k masked). Storage encoding of the
// bool array is unknown (bool bytes / int32 / float32): detect deterministically.
// ---------------------------------------------------------------------------
__global__ void mask_bits_kernel(const u32* __restrict__ raw, u32* __restrict__ outbits) {
    __shared__ int okInt, okFloat;
    int t = threadIdx.x;
    if (t == 0) { okInt = 1; okFloat = 1; }
    __syncthreads();
    int li = 1, lf = 1;
    for (int i = t; i < 1024; i += blockDim.x) {
        u32 v = raw[i];
        if (v > 1u) li = 0;
        if (v != 0u && v != 0x3F800000u) lf = 0;
    }
    if (!li) atomicAnd(&okInt, 0);
    if (!lf) atomicAnd(&okFloat, 0);
    __syncthreads();
    const unsigned char* rb = (const unsigned char*)raw;
    if (t < (BDIM * SDIM) / 32) {
        u32 bits = 0;
        for (int j = 0; j < 32; ++j) {
            int i = t * 32 + j;
            int v;
            if (okInt)        v = (int)raw[i];
            else if (okFloat) v = (raw[i] != 0u) ? 1 : 0;
            else              v = (int)rb[i];
            bits |= (v ? 1u : 0u) << j;
        }
        outbits[t] = bits;
    }
}

// ---------------------------------------------------------------------------
// fp32 -> bf16 bulk conversion (8 elems/thread): query (single matrix)
// ---------------------------------------------------------------------------
__global__ __launch_bounds__(256) void conv_f32_bf16(
    const float* __restrict__ s, u16* __restrict__ d, int n8)
{
    int i = blockIdx.x * 256 + threadIdx.x;
    if (i >= n8) return;
    float4 x0 = ((const float4*)s)[(size_t)i * 2];
    float4 x1 = ((const float4*)s)[(size_t)i * 2 + 1];
    uint4 o;
    o.x = (u32)f2b(x0.x) | ((u32)f2b(x0.y) << 16);
    o.y = (u32)f2b(x0.z) | ((u32)f2b(x0.w) << 16);
    o.z = (u32)f2b(x1.x) | ((u32)f2b(x1.y) << 16);
    o.w = (u32)f2b(x1.z) | ((u32)f2b(x1.w) << 16);
    ((uint4*)d)[i] = o;
}

// ---------------------------------------------------------------------------
// fp32 -> bf16 conversion of all four weight matrices in one dispatch
// ---------------------------------------------------------------------------
__global__ __launch_bounds__(256) void conv4_w(
    const float* __restrict__ w0, const float* __restrict__ w1,
    const float* __restrict__ w2, const float* __restrict__ w3,
    u16* __restrict__ d0, u16* __restrict__ d1,
    u16* __restrict__ d2, u16* __restrict__ d3, int n8)
{
    int m = blockIdx.y;
    const float* s = (m == 0) ? w0 : (m == 1) ? w1 : (m == 2) ? w2 : w3;
    u16* d = (m == 0) ? d0 : (m == 1) ? d1 : (m == 2) ? d2 : d3;
    int i = blockIdx.x * 256 + threadIdx.x;
    if (i >= n8) return;
    float4 x0 = ((const float4*)s)[(size_t)i * 2];
    float4 x1 = ((const float4*)s)[(size_t)i * 2 + 1];
    uint4 o;
    o.x = (u32)f2b(x0.x) | ((u32)f2b(x0.y) << 16);
    o.y = (u32)f2b(x0.z) | ((u32)f2b(x0.w) << 16);
    o.z = (u32)f2b(x1.x) | ((u32)f2b(x1.y) << 16);
    o.w = (u32)f2b(x1.z) | ((u32)f2b(x1.w) << 16);
    ((uint4*)d)[i] = o;
}

// ---------------------------------------------------------------------------
// Fused QKV projection, R7-proven inner loop (64x64 tile, BK=32, 4 waves,
// manual coalesced uint4 staging into stride-56 LDS). N = 3*768 concatenated;
// blockIdx.y picks the matrix (block-uniform).
// Q -> bf16 [bh][s][d]; K -> fragment-major; V -> fragment-major.
// ---------------------------------------------------------------------------
__global__ __launch_bounds__(256) void gemm_qkv(
    const u16* __restrict__ A,
    const u16* __restrict__ wq, const u16* __restrict__ wk, const u16* __restrict__ wv,
    const float* __restrict__ bq, const float* __restrict__ bk, const float* __restrict__ bv,
    u16* __restrict__ qout, u16* __restrict__ kout, u16* __restrict__ vout)
{
    __shared__ u16 Al[64 * 56];
    __shared__ u16 Bl[64 * 56];
    int tid = threadIdx.x;
    int lane = tid & 63, w = tid >> 6;
    int r16 = lane & 15, g4 = lane >> 4;
    int wm = w >> 1, wn = w & 1;
    int mb = blockIdx.x * 64;
    int nbg = blockIdx.y * 64;
    int mid = nbg / EDIM;
    int nb = nbg - mid * EDIM;
    const u16* W = (mid == 0) ? wq : (mid == 1) ? wk : wv;
    const float* bias = (mid == 0) ? bq : (mid == 1) ? bk : bv;
    float scale = (mid == 0) ? SCALE_Q : 1.0f;

    f32x4 acc[2][2];
    acc[0][0] = zero4(); acc[0][1] = zero4(); acc[1][0] = zero4(); acc[1][1] = zero4();

    int srow = tid >> 2, scol = (tid & 3) * 8;

    for (int kb = 0; kb < EDIM; kb += 32) {
        __syncthreads();
        *(uint4*)&Al[srow * 56 + scol] =
            *(const uint4*)&A[(size_t)(mb + srow) * EDIM + kb + scol];
        *(uint4*)&Bl[srow * 56 + scol] =
            *(const uint4*)&W[(size_t)(nb + srow) * EDIM + kb + scol];
        __syncthreads();
        s16x8 a[2], bb[2];
        #pragma unroll
        for (int mi = 0; mi < 2; ++mi)
            a[mi] = *(const s16x8*)&Al[(wm * 32 + mi * 16 + r16) * 56 + g4 * 8];
        #pragma unroll
        for (int ni = 0; ni < 2; ++ni)
            bb[ni] = *(const s16x8*)&Bl[(wn * 32 + ni * 16 + r16) * 56 + g4 * 8];
        #pragma unroll
        for (int mi = 0; mi < 2; ++mi)
            #pragma unroll
            for (int ni = 0; ni < 2; ++ni)
                acc[mi][ni] = mfma16(a[mi], bb[ni], acc[mi][ni]);
    }

    #pragma unroll
    for (int mi = 0; mi < 2; ++mi) {
        #pragma unroll
        for (int ni = 0; ni < 2; ++ni) {
            int n = nb + wn * 32 + ni * 16 + r16;
            float bv_ = bias[n];
            #pragma unroll
            for (int r = 0; r < 4; ++r) {
                int m = mb + wm * 32 + mi * 16 + g4 * 4 + r;
                float c = (acc[mi][ni][r] + bv_) * scale;
                int s_ = m >> 1, b_ = m & 1, h_ = n >> 6, d_ = n & 63;
                if (mid == 0) {
                    qout[((size_t)(b_ * HDIM + h_) * SDIM + s_) * DDIM + d_] = f2b(c);
                } else if (mid == 1) {
                    size_t p = (size_t)(b_ * HDIM + h_) * HFRAG
                             + (size_t)(s_ >> 4) * 1024 + (size_t)((d_ >> 5) & 1) * 512
                             + (size_t)(((d_ >> 3) & 3) * 16 + (s_ & 15)) * 8 + (d_ & 7);
                    kout[p] = f2b(c);
                } else {
                    size_t p = (size_t)(b_ * HDIM + h_) * HFRAG
                             + (size_t)(s_ >> 5) * 2048 + (size_t)((d_ >> 4) & 3) * 512
                             + (size_t)(((s_ >> 3) & 3) * 16 + (d_ & 15)) * 8 + (s_ & 7);
                    vout[p] = f2b(c);
                }
            }
        }
    }
}

// ---------------------------------------------------------------------------
// Output projection: out = attn @ Wo^T + bo (fp32 row-major). R7 inner loop.
// ---------------------------------------------------------------------------
__global__ __launch_bounds__(256) void gemm_out(
    const u16* __restrict__ A, const u16* __restrict__ Wb,
    const float* __restrict__ bias, float* __restrict__ out_rm)
{
    __shared__ u16 Al[64 * 56];
    __shared__ u16 Bl[64 * 56];
    int tid = threadIdx.x;
    int lane = tid & 63, w = tid >> 6;
    int r16 = lane & 15, g4 = lane >> 4;
    int wm = w >> 1, wn = w & 1;
    int mb = blockIdx.x * 64, nb = blockIdx.y * 64;

    f32x4 acc[2][2];
    acc[0][0] = zero4(); acc[0][1] = zero4(); acc[1][0] = zero4(); acc[1][1] = zero4();

    int srow = tid >> 2, scol = (tid & 3) * 8;

    for (int kb = 0; kb < EDIM; kb += 32) {
        __syncthreads();
        *(uint4*)&Al[srow * 56 + scol] =
            *(const uint4*)&A[(size_t)(mb + srow) * EDIM + kb + scol];
        *(uint4*)&Bl[srow * 56 + scol] =
            *(const uint4*)&Wb[(size_t)(nb + srow) * EDIM + kb + scol];
        __syncthreads();
        s16x8 a[2], bb[2];
        #pragma unroll
        for (int mi = 0; mi < 2; ++mi)
            a[mi] = *(const s16x8*)&Al[(wm * 32 + mi * 16 + r16) * 56 + g4 * 8];
        #pragma unroll
        for (int ni = 0; ni < 2; ++ni)
            bb[ni] = *(const s16x8*)&Bl[(wn * 32 + ni * 16 + r16) * 56 + g4 * 8];
        #pragma unroll
        for (int mi = 0; mi < 2; ++mi)
            #pragma unroll
            for (int ni = 0; ni < 2; ++ni)
                acc[mi][ni] = mfma16(a[mi], bb[ni], acc[mi][ni]);
    }

    #pragma unroll
    for (int mi = 0; mi < 2; ++mi) {
        #pragma unroll
        for (int ni = 0; ni < 2; ++ni) {
            int n = nb + wn * 32 + ni * 16 + r16;
            float bv_ = bias[n];
            #pragma unroll
            for (int r = 0; r < 4; ++r) {
                int m = mb + wm * 32 + mi * 16 + g4 * 4 + r;
                out_rm[(size_t)m * EDIM + n] = acc[mi][ni][r] + bv_;
            }
        }
    }
}

// ---------------------------------------------------------------------------
// Fused flash attention v15 — EXACT R12 structure (3-slot bias ring,
// stage(t+2)/vmcnt(17), in-register P transpose, NO launch_bounds) + T5
// s_setprio around the MFMA clusters (independent-wave kernel: the structure
// where setprio measured +4-7%; R9's test of it was confounded).
// ---------------------------------------------------------------------------
struct KV { s16x8 k0, k1, k2, k3, v0, v1, v2, v3; u32 mw; };

__global__ void attn_fused(
    const u16* __restrict__ qw, const u16* __restrict__ kf_g,
    const u16* __restrict__ vf_g, const float* __restrict__ bias,
    const u32* __restrict__ maskBits, u16* __restrict__ attn_out)
{
    __shared__ __align__(1024) unsigned char SM[24576];
    // per wave 12288B: bias ring 3 x 4KB ([32 q][32 k] floats, quad-XOR swizzled)
    // epilogue reuse: As[64][68] f32 (17408B) + Ml/Ll (512B).

    // XCD swizzle: flat%8 = XCD -> contiguous 192-block chunk (3 heads) per XCD
    int flat = blockIdx.y * 64 + blockIdx.x;
    int virt = (flat & 7) * 192 + (flat >> 3);
    int qt = virt & 63, bh = virt >> 6;

    int tid = threadIdx.x;
    int w = tid >> 6, lane = tid & 63;
    int r16 = lane & 15, g4 = lane >> 4;
    int ga = g4 >> 1, gb = g4 & 1;           // for the P shuffle
    int qbase = qt * 32;
    int b_ = bh / HDIM, h_ = bh % HDIM;
    const u16* Q  = qw   + (size_t)bh * SDIM * DDIM;
    const u16* KF = kf_g + (size_t)bh * HFRAG;
    const u16* VF = vf_g + (size_t)bh * HFRAG;
    const float* BrowQ = bias + (size_t)bh * SDIM * SDIM + (size_t)qbase * SDIM;
    const u32* mB = maskBits + b_ * (SDIM / 32);

    unsigned char* wb = SM + w * 12288;
    float* RingW = (float*)wb;               // 3 slots x 1024 floats

    // P-shuffle source lanes (per target lane)
    int srcLo = (2 * gb) * 16 + r16;         // for words 0,1
    int srcHi = (2 * gb + 1) * 16 + r16;     // for words 2,3

    s16x8 qf[2][2];
    #pragma unroll
    for (int h = 0; h < 2; ++h) {
        qf[h][0] = *(const s16x8*)&Q[(size_t)(qbase + 16 * h + r16) * DDIM + g4 * 8];
        qf[h][1] = *(const s16x8*)&Q[(size_t)(qbase + 16 * h + r16) * DDIM + g4 * 8 + 32];
    }

    f32x4 accO[2][4];
    #pragma unroll
    for (int h = 0; h < 2; ++h)
        #pragma unroll
        for (int dt = 0; dt < 4; ++dt) accO[h][dt] = zero4();
    float m_run[2] = {-1e30f, -1e30f}, l_run[2] = {0.f, 0.f};  // column q=r16 (+16h)

    const int k0 = w * KSPLIT;

    auto issue_kv = [&](int t, KV& dst) {
        int tc = t < NIT ? t : NIT - 1;              // clamped (uniform vm count)
        int kbn = k0 + tc * 32;
        const u16* KT = KF + (size_t)(kbn >> 4) * 1024;
        dst.k0 = *(const s16x8*)&KT[lane * 8];
        dst.k1 = *(const s16x8*)&KT[512 + lane * 8];
        dst.k2 = *(const s16x8*)&KT[1024 + lane * 8];
        dst.k3 = *(const s16x8*)&KT[1536 + lane * 8];
        const u16* VT = VF + (size_t)(kbn >> 5) * 2048;
        dst.v0 = *(const s16x8*)&VT[lane * 8];
        dst.v1 = *(const s16x8*)&VT[512 + lane * 8];
        dst.v2 = *(const s16x8*)&VT[1024 + lane * 8];
        dst.v3 = *(const s16x8*)&VT[1536 + lane * 8];
        dst.mw = mB[kbn >> 5];                       // broadcast line, in-pipeline
    };

    // stage bias tile t into ring slot t%3; 4 DMA of 1KB, each 8 rows x 128B;
    // source quad XOR-permuted per row (involution).
    auto stage_bias = [&](int t) {
        int tc = t < NIT ? t : NIT - 1;              // clamped (uniform vm count)
        int kb = k0 + tc * 32;
        unsigned char* slot = wb + (tc % 3) * 4096;
        int sq = (lane & 7) ^ ((lane >> 3) & 7);
        #pragma unroll
        for (int j = 0; j < 4; ++j) {
            int row = j * 8 + (lane >> 3);
            gload_lds16(&BrowQ[(size_t)row * SDIM + kb + sq * 4], slot + j * 1024);
        }
    };

    auto compute = [&](int t, KV& cur) {
        u32 mw = cur.mw;
        const float* Bs = RingW + (t % 3) * 1024;
        // QK^T swapped, both halves: sc[h][kt][r] = S[k=16kt+4g4+r][q=16h+r16]
        f32x4 sc[2][2];
        __builtin_amdgcn_s_setprio(1);
        #pragma unroll
        for (int h = 0; h < 2; ++h) {
            sc[h][0] = mfma16(cur.k1, qf[h][1], mfma16(cur.k0, qf[h][0], zero4()));
            sc[h][1] = mfma16(cur.k3, qf[h][1], mfma16(cur.k2, qf[h][0], zero4()));
        }
        __builtin_amdgcn_s_setprio(0);
        // bias + mask poison
        #pragma unroll
        for (int h = 0; h < 2; ++h) {
            int rr = 16 * h + r16;
            #pragma unroll
            for (int kt = 0; kt < 2; ++kt) {
                float4 bc = *(const float4*)&Bs[rr * 32 + (((4 * kt + g4) ^ (r16 & 7)) * 4)];
                u32 mseg = (mw >> (16 * kt + 4 * g4)) & 0xF;
                sc[h][kt][0] = (mseg & 1) ? -1e30f : sc[h][kt][0] + bc.x;
                sc[h][kt][1] = (mseg & 2) ? -1e30f : sc[h][kt][1] + bc.y;
                sc[h][kt][2] = (mseg & 4) ? -1e30f : sc[h][kt][2] + bc.z;
                sc[h][kt][3] = (mseg & 8) ? -1e30f : sc[h][kt][3] + bc.w;
            }
        }
        // per half: online softmax (column q = 16h+r16, defer-max thr=4),
        // then P pack + in-register transpose to PV A-fragments, then PV.
        #pragma unroll
        for (int h = 0; h < 2; ++h) {
            float pm = fmaxf(
                fmaxf(fmaxf(sc[h][0][0], sc[h][0][1]), fmaxf(sc[h][0][2], sc[h][0][3])),
                fmaxf(fmaxf(sc[h][1][0], sc[h][1][1]), fmaxf(sc[h][1][2], sc[h][1][3])));
            pm = fmaxf(pm, __shfl_xor(pm, 16));
            pm = fmaxf(pm, __shfl_xor(pm, 32));
            bool norescale = __all(pm <= m_run[h] + 4.f);
            float mn = norescale ? m_run[h] : fmaxf(m_run[h], pm);
            float p[8];
            #pragma unroll
            for (int kt = 0; kt < 2; ++kt)
                #pragma unroll
                for (int r = 0; r < 4; ++r)
                    p[kt * 4 + r] = __expf(sc[h][kt][r] - mn);
            float ps = ((p[0] + p[1]) + (p[2] + p[3])) + ((p[4] + p[5]) + (p[6] + p[7]));
            ps += __shfl_xor(ps, 16);
            ps += __shfl_xor(ps, 32);
            if (norescale) {
                l_run[h] += ps;
            } else {
                float alpha = __expf(m_run[h] - mn);
                l_run[h] = l_run[h] * alpha + ps;
                m_run[h] = mn;
                float aR0 = __shfl(alpha, g4 * 4 + 0);
                float aR1 = __shfl(alpha, g4 * 4 + 1);
                float aR2 = __shfl(alpha, g4 * 4 + 2);
                float aR3 = __shfl(alpha, g4 * 4 + 3);
                #pragma unroll
                for (int dt = 0; dt < 4; ++dt) {
                    accO[h][dt][0] *= aR0;
                    accO[h][dt][1] *= aR1;
                    accO[h][dt][2] *= aR2;
                    accO[h][dt][3] *= aR3;
                }
            }
            // pack column-form P; word m covers k = 16(m>>1)+4g4+2(m&1)+{0,1}
            u32 W0 = cvt_pk_bf16(p[0], p[1]);
            u32 W1 = cvt_pk_bf16(p[2], p[3]);
            u32 W2 = cvt_pk_bf16(p[4], p[5]);
            u32 W3 = cvt_pk_bf16(p[6], p[7]);
            // transpose: target word w <- src lane (w<2 ? srcLo : srcHi),
            // src word (2a + (w&1)); select by a = g4>>1
            u32 o0A = (u32)__shfl((int)W0, srcLo), o0B = (u32)__shfl((int)W2, srcLo);
            u32 o1A = (u32)__shfl((int)W1, srcLo), o1B = (u32)__shfl((int)W3, srcLo);
            u32 o2A = (u32)__shfl((int)W0, srcHi), o2B = (u32)__shfl((int)W2, srcHi);
            u32 o3A = (u32)__shfl((int)W1, srcHi), o3B = (u32)__shfl((int)W3, srcHi);
            uint4 pw;
            pw.x = ga ? o0B : o0A;
            pw.y = ga ? o1B : o1A;
            pw.z = ga ? o2B : o2A;
            pw.w = ga ? o3B : o3A;
            s16x8 pf = __builtin_bit_cast(s16x8, pw);
            __builtin_amdgcn_s_setprio(1);
            accO[h][0] = mfma16(pf, cur.v0, accO[h][0]);
            accO[h][1] = mfma16(pf, cur.v1, accO[h][1]);
            accO[h][2] = mfma16(pf, cur.v2, accO[h][2]);
            accO[h][3] = mfma16(pf, cur.v3, accO[h][3]);
            __builtin_amdgcn_s_setprio(0);
        }
    };

    // prologue: kv(0) + bias tiles 0,1 staged (depth-2)
    KV A, B;
    issue_kv(0, A);
    stage_bias(0);
    stage_bias(1);

    for (int t = 0; t < NIT; t += 2) {
        issue_kv(t + 1, B);
        stage_bias(t + 2);
        asm volatile("s_waitcnt vmcnt(17)" ::: "memory");
        __builtin_amdgcn_sched_barrier(0);
        compute(t, A);

        issue_kv(t + 2, A);
        stage_bias(t + 3);
        asm volatile("s_waitcnt vmcnt(17)" ::: "memory");
        __builtin_amdgcn_sched_barrier(0);
        compute(t + 1, B);
    }

    // ---- combine the two waves' partials (reuse LDS) ----
    __syncthreads();
    float* As = (float*)SM;                 // [64][68]
    float* Ml = (float*)(SM + 17408);       // [64]
    float* Ll = Ml + 64;
    #pragma unroll
    for (int h = 0; h < 2; ++h)
        #pragma unroll
        for (int dt = 0; dt < 4; ++dt)
            #pragma unroll
            for (int r = 0; r < 4; ++r)
                As[(size_t)(w * 32 + 16 * h + g4 * 4 + r) * 68 + dt * 16 + r16] = accO[h][dt][r];
    if (g4 == 0) {
        #pragma unroll
        for (int h = 0; h < 2; ++h) {
            Ml[w * 32 + 16 * h + r16] = m_run[h];
            Ll[w * 32 + 16 * h + r16] = l_run[h];
        }
    }
    __syncthreads();

    #pragma unroll
    for (int h = 0; h < 2; ++h) {
        #pragma unroll
        for (int dg = 0; dg < 2; ++dg) {
            int d = w * 32 + dg * 16 + r16;
            #pragma unroll
            for (int r = 0; r < 4; ++r) {
                int q = 16 * h + g4 * 4 + r;
                float m0 = Ml[q], m1 = Ml[32 + q];
                float mt = fmaxf(m0, m1);
                float e0 = __expf(m0 - mt), e1 = __expf(m1 - mt);
                float lt = Ll[q] * e0 + Ll[32 + q] * e1;
                float o = (As[(size_t)q * 68 + d] * e0 + As[(size_t)(32 + q) * 68 + d] * e1) / lt;
                attn_out[((size_t)(qbase + q) * BDIM + b_) * EDIM + h_ * DDIM + d] = f2b(o);
            }
        }
    }
}

extern "C" void kernel_launch(void* const* d_in, const int* in_sizes, int n_in,
                              void* d_out, int out_size, void* d_ws, size_t ws_size,
                              hipStream_t stream) {
    const float* query     = (const float*)d_in[0];
    const float* attn_bias = (const float*)d_in[1];
    const u32*   mask_raw  = (const u32*)d_in[2];
    const float* Wq = (const float*)d_in[3];
    const float* bq = (const float*)d_in[4];
    const float* Wk = (const float*)d_in[5];
    const float* bk = (const float*)d_in[6];
    const float* Wv = (const float*)d_in[7];
    const float* bv = (const float*)d_in[8];
    const float* Wo = (const float*)d_in[9];
    const float* bo = (const float*)d_in[10];
    float* out = (float*)d_out;

    // workspace layout: maskBits(16KB) | qws | kws | vws | aws(=qbf) | 4x Wbf
    char* ws = (char*)d_ws;
    u32* maskB = (u32*)ws;
    const size_t HEADSZ = (size_t)BDIM * HDIM * SDIM * DDIM;  // 3,145,728 elems
    const size_t WSZ = (size_t)EDIM * EDIM;                   //   589,824 elems
    u16* qws = (u16*)(ws + 16384);
    u16* kws = qws + HEADSZ;
    u16* vws = kws + HEADSZ;
    u16* aws = vws + HEADSZ;      // attn out; doubles as bf16 query (qbf)
    u16* qbf = aws;
    u16* wWq = aws + HEADSZ;
    u16* wWk = wWq + WSZ;
    u16* wWv = wWk + WSZ;
    u16* wWo = wWv + WSZ;

    mask_bits_kernel<<<1, 256, 0, stream>>>(mask_raw, maskB);

    conv_f32_bf16<<<(int)(MDIM * EDIM / 8 / 256), 256, 0, stream>>>(query, qbf, MDIM * EDIM / 8);
    dim3 gc((int)(WSZ / 8 / 256), 4);
    conv4_w<<<gc, 256, 0, stream>>>(Wq, Wk, Wv, Wo, wWq, wWk, wWv, wWo, (int)(WSZ / 8));

    dim3 gq(MDIM / 64, (3 * EDIM) / 64);
    gemm_qkv<<<gq, 256, 0, stream>>>(qbf, wWq, wWk, wWv, bq, bk, bv, qws, kws, vws);

    dim3 ga(64, BDIM * HDIM);
    attn_fused<<<ga, 128, 0, stream>>>(qws, kws, vws, attn_bias, maskB, aws);

    dim3 go(MDIM / 64, EDIM / 64);
    gemm_out<<<go, 256, 0, stream>>>(aws, wWo, bo, out);
}

// Round 16
// 227.382 us; speedup vs baseline: 1.8870x; 1.8870x over previous
//
#include <hip/hip_runtime.h>
#include <hip/hip_bf16.h>

typedef __attribute__((ext_vector_type(8))) short s16x8;   // 8 bf16 (4 VGPRs)
typedef __attribute__((ext_vector_type(4))) float f32x4;
typedef unsigned short u16;
typedef unsigned int u32;

#define SDIM 2048
#define BDIM 2
#define HDIM 12
#define DDIM 64
#define EDIM 768
#define MDIM 4096          // S*B rows
#define SCALE_Q 0.125f     // D^-0.5
#define KSPLIT 1024        // keys per wave (2 waves split the 2048-key range)
#define NIT (KSPLIT / 32)  // 32 bodies per wave
#define HFRAG 131072       // per-head fragment-tensor elements (2048*64)

static __device__ __forceinline__ f32x4 zero4() {
    f32x4 v; v[0] = v[1] = v[2] = v[3] = 0.f; return v;
}

// fp32 -> bf16 bits, round-to-nearest-even
static __device__ __forceinline__ u16 f2b(float x) {
    u32 u = __builtin_bit_cast(u32, x);
    u32 lsb = (u >> 16) & 1u;
    u += 0x7fffu + lsb;
    return (u16)(u >> 16);
}

// pack two f32 -> one u32 of 2x bf16 (RNE) via HW instruction
static __device__ __forceinline__ u32 cvt_pk_bf16(float lo, float hi) {
    u32 r;
    asm("v_cvt_pk_bf16_f32 %0, %1, %2" : "=v"(r) : "v"(lo), "v"(hi));
    return r;
}

static __device__ __forceinline__ f32x4 mfma16(s16x8 a, s16x8 b, f32x4 c) {
    return __builtin_amdgcn_mfma_f32_16x16x32_bf16(a, b, c, 0, 0, 0);
}

// async global -> LDS, 16B per lane. LDS dest = wave-uniform base + lane*16.
static __device__ __forceinline__ void gload_lds16(const void* g, void* l) {
    __builtin_amdgcn_global_load_lds(
        (const __attribute__((address_space(1))) void*)g,
        (__attribute__((address_space(3))) void*)l, 16, 0, 0);
}

// ---------------------------------------------------------------------------
// mask -> bitmask (128 u32; bit k = key k masked). Storage encoding of the
// bool array is unknown (bool bytes / int32 / float32): detect deterministically.
// ---------------------------------------------------------------------------
__global__ void mask_bits_kernel(const u32* __restrict__ raw, u32* __restrict__ outbits) {
    __shared__ int okInt, okFloat;
    int t = threadIdx.x;
    if (t == 0) { okInt = 1; okFloat = 1; }
    __syncthreads();
    int li = 1, lf = 1;
    for (int i = t; i < 1024; i += blockDim.x) {
        u32 v = raw[i];
        if (v > 1u) li = 0;
        if (v != 0u && v != 0x3F800000u) lf = 0;
    }
    if (!li) atomicAnd(&okInt, 0);
    if (!lf) atomicAnd(&okFloat, 0);
    __syncthreads();
    const unsigned char* rb = (const unsigned char*)raw;
    if (t < (BDIM * SDIM) / 32) {
        u32 bits = 0;
        for (int j = 0; j < 32; ++j) {
            int i = t * 32 + j;
            int v;
            if (okInt)        v = (int)raw[i];
            else if (okFloat) v = (raw[i] != 0u) ? 1 : 0;
            else              v = (int)rb[i];
            bits |= (v ? 1u : 0u) << j;
        }
        outbits[t] = bits;
    }
}

// ---------------------------------------------------------------------------
// fp32 -> bf16 bulk conversion (8 elems/thread): query (single matrix)
// ---------------------------------------------------------------------------
__global__ __launch_bounds__(256) void conv_f32_bf16(
    const float* __restrict__ s, u16* __restrict__ d, int n8)
{
    int i = blockIdx.x * 256 + threadIdx.x;
    if (i >= n8) return;
    float4 x0 = ((const float4*)s)[(size_t)i * 2];
    float4 x1 = ((const float4*)s)[(size_t)i * 2 + 1];
    uint4 o;
    o.x = (u32)f2b(x0.x) | ((u32)f2b(x0.y) << 16);
    o.y = (u32)f2b(x0.z) | ((u32)f2b(x0.w) << 16);
    o.z = (u32)f2b(x1.x) | ((u32)f2b(x1.y) << 16);
    o.w = (u32)f2b(x1.z) | ((u32)f2b(x1.w) << 16);
    ((uint4*)d)[i] = o;
}

// ---------------------------------------------------------------------------
// fp32 -> bf16 conversion of all four weight matrices in one dispatch
// ---------------------------------------------------------------------------
__global__ __launch_bounds__(256) void conv4_w(
    const float* __restrict__ w0, const float* __restrict__ w1,
    const float* __restrict__ w2, const float* __restrict__ w3,
    u16* __restrict__ d0, u16* __restrict__ d1,
    u16* __restrict__ d2, u16* __restrict__ d3, int n8)
{
    int m = blockIdx.y;
    const float* s = (m == 0) ? w0 : (m == 1) ? w1 : (m == 2) ? w2 : w3;
    u16* d = (m == 0) ? d0 : (m == 1) ? d1 : (m == 2) ? d2 : d3;
    int i = blockIdx.x * 256 + threadIdx.x;
    if (i >= n8) return;
    float4 x0 = ((const float4*)s)[(size_t)i * 2];
    float4 x1 = ((const float4*)s)[(size_t)i * 2 + 1];
    uint4 o;
    o.x = (u32)f2b(x0.x) | ((u32)f2b(x0.y) << 16);
    o.y = (u32)f2b(x0.z) | ((u32)f2b(x0.w) << 16);
    o.z = (u32)f2b(x1.x) | ((u32)f2b(x1.y) << 16);
    o.w = (u32)f2b(x1.z) | ((u32)f2b(x1.w) << 16);
    ((uint4*)d)[i] = o;
}

// ---------------------------------------------------------------------------
// Fused QKV projection, R7-proven inner loop (64x64 tile, BK=32, 4 waves,
// manual coalesced uint4 staging into stride-56 LDS). N = 3*768 concatenated;
// blockIdx.y picks the matrix (block-uniform).
// Q -> bf16 [bh][s][d]; K -> fragment-major; V -> fragment-major.
// ---------------------------------------------------------------------------
__global__ __launch_bounds__(256) void gemm_qkv(
    const u16* __restrict__ A,
    const u16* __restrict__ wq, const u16* __restrict__ wk, const u16* __restrict__ wv,
    const float* __restrict__ bq, const float* __restrict__ bk, const float* __restrict__ bv,
    u16* __restrict__ qout, u16* __restrict__ kout, u16* __restrict__ vout)
{
    __shared__ u16 Al[64 * 56];
    __shared__ u16 Bl[64 * 56];
    int tid = threadIdx.x;
    int lane = tid & 63, w = tid >> 6;
    int r16 = lane & 15, g4 = lane >> 4;
    int wm = w >> 1, wn = w & 1;
    int mb = blockIdx.x * 64;
    int nbg = blockIdx.y * 64;
    int mid = nbg / EDIM;
    int nb = nbg - mid * EDIM;
    const u16* W = (mid == 0) ? wq : (mid == 1) ? wk : wv;
    const float* bias = (mid == 0) ? bq : (mid == 1) ? bk : bv;
    float scale = (mid == 0) ? SCALE_Q : 1.0f;

    f32x4 acc[2][2];
    acc[0][0] = zero4(); acc[0][1] = zero4(); acc[1][0] = zero4(); acc[1][1] = zero4();

    int srow = tid >> 2, scol = (tid & 3) * 8;

    for (int kb = 0; kb < EDIM; kb += 32) {
        __syncthreads();
        *(uint4*)&Al[srow * 56 + scol] =
            *(const uint4*)&A[(size_t)(mb + srow) * EDIM + kb + scol];
        *(uint4*)&Bl[srow * 56 + scol] =
            *(const uint4*)&W[(size_t)(nb + srow) * EDIM + kb + scol];
        __syncthreads();
        s16x8 a[2], bb[2];
        #pragma unroll
        for (int mi = 0; mi < 2; ++mi)
            a[mi] = *(const s16x8*)&Al[(wm * 32 + mi * 16 + r16) * 56 + g4 * 8];
        #pragma unroll
        for (int ni = 0; ni < 2; ++ni)
            bb[ni] = *(const s16x8*)&Bl[(wn * 32 + ni * 16 + r16) * 56 + g4 * 8];
        #pragma unroll
        for (int mi = 0; mi < 2; ++mi)
            #pragma unroll
            for (int ni = 0; ni < 2; ++ni)
                acc[mi][ni] = mfma16(a[mi], bb[ni], acc[mi][ni]);
    }

    #pragma unroll
    for (int mi = 0; mi < 2; ++mi) {
        #pragma unroll
        for (int ni = 0; ni < 2; ++ni) {
            int n = nb + wn * 32 + ni * 16 + r16;
            float bv_ = bias[n];
            #pragma unroll
            for (int r = 0; r < 4; ++r) {
                int m = mb + wm * 32 + mi * 16 + g4 * 4 + r;
                float c = (acc[mi][ni][r] + bv_) * scale;
                int s_ = m >> 1, b_ = m & 1, h_ = n >> 6, d_ = n & 63;
                if (mid == 0) {
                    qout[((size_t)(b_ * HDIM + h_) * SDIM + s_) * DDIM + d_] = f2b(c);
                } else if (mid == 1) {
                    size_t p = (size_t)(b_ * HDIM + h_) * HFRAG
                             + (size_t)(s_ >> 4) * 1024 + (size_t)((d_ >> 5) & 1) * 512
                             + (size_t)(((d_ >> 3) & 3) * 16 + (s_ & 15)) * 8 + (d_ & 7);
                    kout[p] = f2b(c);
                } else {
                    size_t p = (size_t)(b_ * HDIM + h_) * HFRAG
                             + (size_t)(s_ >> 5) * 2048 + (size_t)((d_ >> 4) & 3) * 512
                             + (size_t)(((s_ >> 3) & 3) * 16 + (d_ & 15)) * 8 + (s_ & 7);
                    vout[p] = f2b(c);
                }
            }
        }
    }
}

// ---------------------------------------------------------------------------
// Output projection: out = attn @ Wo^T + bo (fp32 row-major). R7 inner loop.
// ---------------------------------------------------------------------------
__global__ __launch_bounds__(256) void gemm_out(
    const u16* __restrict__ A, const u16* __restrict__ Wb,
    const float* __restrict__ bias, float* __restrict__ out_rm)
{
    __shared__ u16 Al[64 * 56];
    __shared__ u16 Bl[64 * 56];
    int tid = threadIdx.x;
    int lane = tid & 63, w = tid >> 6;
    int r16 = lane & 15, g4 = lane >> 4;
    int wm = w >> 1, wn = w & 1;
    int mb = blockIdx.x * 64, nb = blockIdx.y * 64;

    f32x4 acc[2][2];
    acc[0][0] = zero4(); acc[0][1] = zero4(); acc[1][0] = zero4(); acc[1][1] = zero4();

    int srow = tid >> 2, scol = (tid & 3) * 8;

    for (int kb = 0; kb < EDIM; kb += 32) {
        __syncthreads();
        *(uint4*)&Al[srow * 56 + scol] =
            *(const uint4*)&A[(size_t)(mb + srow) * EDIM + kb + scol];
        *(uint4*)&Bl[srow * 56 + scol] =
            *(const uint4*)&Wb[(size_t)(nb + srow) * EDIM + kb + scol];
        __syncthreads();
        s16x8 a[2], bb[2];
        #pragma unroll
        for (int mi = 0; mi < 2; ++mi)
            a[mi] = *(const s16x8*)&Al[(wm * 32 + mi * 16 + r16) * 56 + g4 * 8];
        #pragma unroll
        for (int ni = 0; ni < 2; ++ni)
            bb[ni] = *(const s16x8*)&Bl[(wn * 32 + ni * 16 + r16) * 56 + g4 * 8];
        #pragma unroll
        for (int mi = 0; mi < 2; ++mi)
            #pragma unroll
            for (int ni = 0; ni < 2; ++ni)
                acc[mi][ni] = mfma16(a[mi], bb[ni], acc[mi][ni]);
    }

    #pragma unroll
    for (int mi = 0; mi < 2; ++mi) {
        #pragma unroll
        for (int ni = 0; ni < 2; ++ni) {
            int n = nb + wn * 32 + ni * 16 + r16;
            float bv_ = bias[n];
            #pragma unroll
            for (int r = 0; r < 4; ++r) {
                int m = mb + wm * 32 + mi * 16 + g4 * 4 + r;
                out_rm[(size_t)m * EDIM + n] = acc[mi][ni][r] + bv_;
            }
        }
    }
}

// ---------------------------------------------------------------------------
// Fused flash attention v16 — R12 structure (3-slot bias ring, stage(t+2)/
// vmcnt(17), in-register P transpose) with __launch_bounds__(128) — block-size
// only, the form R12 used; R15's spill came from omitting it (hipcc then
// assumes 1024-thread blocks -> 64-VGPR cap). Plus T5 s_setprio around the
// MFMA clusters (the clean test) and conv4_w fusion.
// ---------------------------------------------------------------------------
struct KV { s16x8 k0, k1, k2, k3, v0, v1, v2, v3; u32 mw; };

__global__ __launch_bounds__(128) void attn_fused(
    const u16* __restrict__ qw, const u16* __restrict__ kf_g,
    const u16* __restrict__ vf_g, const float* __restrict__ bias,
    const u32* __restrict__ maskBits, u16* __restrict__ attn_out)
{
    __shared__ __align__(1024) unsigned char SM[24576];
    // per wave 12288B: bias ring 3 x 4KB ([32 q][32 k] floats, quad-XOR swizzled)
    // epilogue reuse: As[64][68] f32 (17408B) + Ml/Ll (512B).

    // XCD swizzle: flat%8 = XCD -> contiguous 192-block chunk (3 heads) per XCD
    int flat = blockIdx.y * 64 + blockIdx.x;
    int virt = (flat & 7) * 192 + (flat >> 3);
    int qt = virt & 63, bh = virt >> 6;

    int tid = threadIdx.x;
    int w = tid >> 6, lane = tid & 63;
    int r16 = lane & 15, g4 = lane >> 4;
    int ga = g4 >> 1, gb = g4 & 1;           // for the P shuffle
    int qbase = qt * 32;
    int b_ = bh / HDIM, h_ = bh % HDIM;
    const u16* Q  = qw   + (size_t)bh * SDIM * DDIM;
    const u16* KF = kf_g + (size_t)bh * HFRAG;
    const u16* VF = vf_g + (size_t)bh * HFRAG;
    const float* BrowQ = bias + (size_t)bh * SDIM * SDIM + (size_t)qbase * SDIM;
    const u32* mB = maskBits + b_ * (SDIM / 32);

    unsigned char* wb = SM + w * 12288;
    float* RingW = (float*)wb;               // 3 slots x 1024 floats

    // P-shuffle source lanes (per target lane)
    int srcLo = (2 * gb) * 16 + r16;         // for words 0,1
    int srcHi = (2 * gb + 1) * 16 + r16;     // for words 2,3

    s16x8 qf[2][2];
    #pragma unroll
    for (int h = 0; h < 2; ++h) {
        qf[h][0] = *(const s16x8*)&Q[(size_t)(qbase + 16 * h + r16) * DDIM + g4 * 8];
        qf[h][1] = *(const s16x8*)&Q[(size_t)(qbase + 16 * h + r16) * DDIM + g4 * 8 + 32];
    }

    f32x4 accO[2][4];
    #pragma unroll
    for (int h = 0; h < 2; ++h)
        #pragma unroll
        for (int dt = 0; dt < 4; ++dt) accO[h][dt] = zero4();
    float m_run[2] = {-1e30f, -1e30f}, l_run[2] = {0.f, 0.f};  // column q=r16 (+16h)

    const int k0 = w * KSPLIT;

    auto issue_kv = [&](int t, KV& dst) {
        int tc = t < NIT ? t : NIT - 1;              // clamped (uniform vm count)
        int kbn = k0 + tc * 32;
        const u16* KT = KF + (size_t)(kbn >> 4) * 1024;
        dst.k0 = *(const s16x8*)&KT[lane * 8];
        dst.k1 = *(const s16x8*)&KT[512 + lane * 8];
        dst.k2 = *(const s16x8*)&KT[1024 + lane * 8];
        dst.k3 = *(const s16x8*)&KT[1536 + lane * 8];
        const u16* VT = VF + (size_t)(kbn >> 5) * 2048;
        dst.v0 = *(const s16x8*)&VT[lane * 8];
        dst.v1 = *(const s16x8*)&VT[512 + lane * 8];
        dst.v2 = *(const s16x8*)&VT[1024 + lane * 8];
        dst.v3 = *(const s16x8*)&VT[1536 + lane * 8];
        dst.mw = mB[kbn >> 5];                       // broadcast line, in-pipeline
    };

    // stage bias tile t into ring slot t%3; 4 DMA of 1KB, each 8 rows x 128B;
    // source quad XOR-permuted per row (involution).
    auto stage_bias = [&](int t) {
        int tc = t < NIT ? t : NIT - 1;              // clamped (uniform vm count)
        int kb = k0 + tc * 32;
        unsigned char* slot = wb + (tc % 3) * 4096;
        int sq = (lane & 7) ^ ((lane >> 3) & 7);
        #pragma unroll
        for (int j = 0; j < 4; ++j) {
            int row = j * 8 + (lane >> 3);
            gload_lds16(&BrowQ[(size_t)row * SDIM + kb + sq * 4], slot + j * 1024);
        }
    };

    auto compute = [&](int t, KV& cur) {
        u32 mw = cur.mw;
        const float* Bs = RingW + (t % 3) * 1024;
        // QK^T swapped, both halves: sc[h][kt][r] = S[k=16kt+4g4+r][q=16h+r16]
        f32x4 sc[2][2];
        __builtin_amdgcn_s_setprio(1);
        #pragma unroll
        for (int h = 0; h < 2; ++h) {
            sc[h][0] = mfma16(cur.k1, qf[h][1], mfma16(cur.k0, qf[h][0], zero4()));
            sc[h][1] = mfma16(cur.k3, qf[h][1], mfma16(cur.k2, qf[h][0], zero4()));
        }
        __builtin_amdgcn_s_setprio(0);
        // bias + mask poison
        #pragma unroll
        for (int h = 0; h < 2; ++h) {
            int rr = 16 * h + r16;
            #pragma unroll
            for (int kt = 0; kt < 2; ++kt) {
                float4 bc = *(const float4*)&Bs[rr * 32 + (((4 * kt + g4) ^ (r16 & 7)) * 4)];
                u32 mseg = (mw >> (16 * kt + 4 * g4)) & 0xF;
                sc[h][kt][0] = (mseg & 1) ? -1e30f : sc[h][kt][0] + bc.x;
                sc[h][kt][1] = (mseg & 2) ? -1e30f : sc[h][kt][1] + bc.y;
                sc[h][kt][2] = (mseg & 4) ? -1e30f : sc[h][kt][2] + bc.z;
                sc[h][kt][3] = (mseg & 8) ? -1e30f : sc[h][kt][3] + bc.w;
            }
        }
        // per half: online softmax (column q = 16h+r16, defer-max thr=4),
        // then P pack + in-register transpose to PV A-fragments, then PV.
        #pragma unroll
        for (int h = 0; h < 2; ++h) {
            float pm = fmaxf(
                fmaxf(fmaxf(sc[h][0][0], sc[h][0][1]), fmaxf(sc[h][0][2], sc[h][0][3])),
                fmaxf(fmaxf(sc[h][1][0], sc[h][1][1]), fmaxf(sc[h][1][2], sc[h][1][3])));
            pm = fmaxf(pm, __shfl_xor(pm, 16));
            pm = fmaxf(pm, __shfl_xor(pm, 32));
            bool norescale = __all(pm <= m_run[h] + 4.f);
            float mn = norescale ? m_run[h] : fmaxf(m_run[h], pm);
            float p[8];
            #pragma unroll
            for (int kt = 0; kt < 2; ++kt)
                #pragma unroll
                for (int r = 0; r < 4; ++r)
                    p[kt * 4 + r] = __expf(sc[h][kt][r] - mn);
            float ps = ((p[0] + p[1]) + (p[2] + p[3])) + ((p[4] + p[5]) + (p[6] + p[7]));
            ps += __shfl_xor(ps, 16);
            ps += __shfl_xor(ps, 32);
            if (norescale) {
                l_run[h] += ps;
            } else {
                float alpha = __expf(m_run[h] - mn);
                l_run[h] = l_run[h] * alpha + ps;
                m_run[h] = mn;
                float aR0 = __shfl(alpha, g4 * 4 + 0);
                float aR1 = __shfl(alpha, g4 * 4 + 1);
                float aR2 = __shfl(alpha, g4 * 4 + 2);
                float aR3 = __shfl(alpha, g4 * 4 + 3);
                #pragma unroll
                for (int dt = 0; dt < 4; ++dt) {
                    accO[h][dt][0] *= aR0;
                    accO[h][dt][1] *= aR1;
                    accO[h][dt][2] *= aR2;
                    accO[h][dt][3] *= aR3;
                }
            }
            // pack column-form P; word m covers k = 16(m>>1)+4g4+2(m&1)+{0,1}
            u32 W0 = cvt_pk_bf16(p[0], p[1]);
            u32 W1 = cvt_pk_bf16(p[2], p[3]);
            u32 W2 = cvt_pk_bf16(p[4], p[5]);
            u32 W3 = cvt_pk_bf16(p[6], p[7]);
            // transpose: target word w <- src lane (w<2 ? srcLo : srcHi),
            // src word (2a + (w&1)); select by a = g4>>1
            u32 o0A = (u32)__shfl((int)W0, srcLo), o0B = (u32)__shfl((int)W2, srcLo);
            u32 o1A = (u32)__shfl((int)W1, srcLo), o1B = (u32)__shfl((int)W3, srcLo);
            u32 o2A = (u32)__shfl((int)W0, srcHi), o2B = (u32)__shfl((int)W2, srcHi);
            u32 o3A = (u32)__shfl((int)W1, srcHi), o3B = (u32)__shfl((int)W3, srcHi);
            uint4 pw;
            pw.x = ga ? o0B : o0A;
            pw.y = ga ? o1B : o1A;
            pw.z = ga ? o2B : o2A;
            pw.w = ga ? o3B : o3A;
            s16x8 pf = __builtin_bit_cast(s16x8, pw);
            __builtin_amdgcn_s_setprio(1);
            accO[h][0] = mfma16(pf, cur.v0, accO[h][0]);
            accO[h][1] = mfma16(pf, cur.v1, accO[h][1]);
            accO[h][2] = mfma16(pf, cur.v2, accO[h][2]);
            accO[h][3] = mfma16(pf, cur.v3, accO[h][3]);
            __builtin_amdgcn_s_setprio(0);
        }
    };

    // prologue: kv(0) + bias tiles 0,1 staged (depth-2)
    KV A, B;
    issue_kv(0, A);
    stage_bias(0);
    stage_bias(1);

    for (int t = 0; t < NIT; t += 2) {
        issue_kv(t + 1, B);
        stage_bias(t + 2);
        asm volatile("s_waitcnt vmcnt(17)" ::: "memory");
        __builtin_amdgcn_sched_barrier(0);
        compute(t, A);

        issue_kv(t + 2, A);
        stage_bias(t + 3);
        asm volatile("s_waitcnt vmcnt(17)" ::: "memory");
        __builtin_amdgcn_sched_barrier(0);
        compute(t + 1, B);
    }

    // ---- combine the two waves' partials (reuse LDS) ----
    __syncthreads();
    float* As = (float*)SM;                 // [64][68]
    float* Ml = (float*)(SM + 17408);       // [64]
    float* Ll = Ml + 64;
    #pragma unroll
    for (int h = 0; h < 2; ++h)
        #pragma unroll
        for (int dt = 0; dt < 4; ++dt)
            #pragma unroll
            for (int r = 0; r < 4; ++r)
                As[(size_t)(w * 32 + 16 * h + g4 * 4 + r) * 68 + dt * 16 + r16] = accO[h][dt][r];
    if (g4 == 0) {
        #pragma unroll
        for (int h = 0; h < 2; ++h) {
            Ml[w * 32 + 16 * h + r16] = m_run[h];
            Ll[w * 32 + 16 * h + r16] = l_run[h];
        }
    }
    __syncthreads();

    #pragma unroll
    for (int h = 0; h < 2; ++h) {
        #pragma unroll
        for (int dg = 0; dg < 2; ++dg) {
            int d = w * 32 + dg * 16 + r16;
            #pragma unroll
            for (int r = 0; r < 4; ++r) {
                int q = 16 * h + g4 * 4 + r;
                float m0 = Ml[q], m1 = Ml[32 + q];
                float mt = fmaxf(m0, m1);
                float e0 = __expf(m0 - mt), e1 = __expf(m1 - mt);
                float lt = Ll[q] * e0 + Ll[32 + q] * e1;
                float o = (As[(size_t)q * 68 + d] * e0 + As[(size_t)(32 + q) * 68 + d] * e1) / lt;
                attn_out[((size_t)(qbase + q) * BDIM + b_) * EDIM + h_ * DDIM + d] = f2b(o);
            }
        }
    }
}

extern "C" void kernel_launch(void* const* d_in, const int* in_sizes, int n_in,
                              void* d_out, int out_size, void* d_ws, size_t ws_size,
                              hipStream_t stream) {
    const float* query     = (const float*)d_in[0];
    const float* attn_bias = (const float*)d_in[1];
    const u32*   mask_raw  = (const u32*)d_in[2];
    const float* Wq = (const float*)d_in[3];
    const float* bq = (const float*)d_in[4];
    const float* Wk = (const float*)d_in[5];
    const float* bk = (const float*)d_in[6];
    const float* Wv = (const float*)d_in[7];
    const float* bv = (const float*)d_in[8];
    const float* Wo = (const float*)d_in[9];
    const float* bo = (const float*)d_in[10];
    float* out = (float*)d_out;

    // workspace layout: maskBits(16KB) | qws | kws | vws | aws(=qbf) | 4x Wbf
    char* ws = (char*)d_ws;
    u32* maskB = (u32*)ws;
    const size_t HEADSZ = (size_t)BDIM * HDIM * SDIM * DDIM;  // 3,145,728 elems
    const size_t WSZ = (size_t)EDIM * EDIM;                   //   589,824 elems
    u16* qws = (u16*)(ws + 16384);
    u16* kws = qws + HEADSZ;
    u16* vws = kws + HEADSZ;
    u16* aws = vws + HEADSZ;      // attn out; doubles as bf16 query (qbf)
    u16* qbf = aws;
    u16* wWq = aws + HEADSZ;
    u16* wWk = wWq + WSZ;
    u16* wWv = wWk + WSZ;
    u16* wWo = wWv + WSZ;

    mask_bits_kernel<<<1, 256, 0, stream>>>(mask_raw, maskB);

    conv_f32_bf16<<<(int)(MDIM * EDIM / 8 / 256), 256, 0, stream>>>(query, qbf, MDIM * EDIM / 8);
    dim3 gc((int)(WSZ / 8 / 256), 4);
    conv4_w<<<gc, 256, 0, stream>>>(Wq, Wk, Wv, Wo, wWq, wWk, wWv, wWo, (int)(WSZ / 8));

    dim3 gq(MDIM / 64, (3 * EDIM) / 64);
    gemm_qkv<<<gq, 256, 0, stream>>>(qbf, wWq, wWk, wWv, bq, bk, bv, qws, kws, vws);

    dim3 ga(64, BDIM * HDIM);
    attn_fused<<<ga, 128, 0, stream>>>(qws, kws, vws, attn_bias, maskB, aws);

    dim3 go(MDIM / 64, EDIM / 64);
    gemm_out<<<go, 256, 0, stream>>>(aws, wWo, bo, out);
}

// Round 17
// 222.951 us; speedup vs baseline: 1.9245x; 1.0199x over previous
//
#include <hip/hip_runtime.h>
#include <hip/hip_bf16.h>

typedef __attribute__((ext_vector_type(8))) short s16x8;   // 8 bf16 (4 VGPRs)
typedef __attribute__((ext_vector_type(4))) float f32x4;
typedef unsigned short u16;
typedef unsigned int u32;

#define SDIM 2048
#define BDIM 2
#define HDIM 12
#define DDIM 64
#define EDIM 768
#define MDIM 4096          // S*B rows
#define SCALE_Q 0.125f     // D^-0.5
#define KSPLIT 1024        // keys per wave (2 waves split the 2048-key range)
#define NIT (KSPLIT / 32)  // 32 bodies per wave
#define HFRAG 131072       // per-head fragment-tensor elements (2048*64)

static __device__ __forceinline__ f32x4 zero4() {
    f32x4 v; v[0] = v[1] = v[2] = v[3] = 0.f; return v;
}

// fp32 -> bf16 bits, round-to-nearest-even
static __device__ __forceinline__ u16 f2b(float x) {
    u32 u = __builtin_bit_cast(u32, x);
    u32 lsb = (u >> 16) & 1u;
    u += 0x7fffu + lsb;
    return (u16)(u >> 16);
}

// pack two f32 -> one u32 of 2x bf16 (RNE) via HW instruction
static __device__ __forceinline__ u32 cvt_pk_bf16(float lo, float hi) {
    u32 r;
    asm("v_cvt_pk_bf16_f32 %0, %1, %2" : "=v"(r) : "v"(lo), "v"(hi));
    return r;
}

static __device__ __forceinline__ f32x4 mfma16(s16x8 a, s16x8 b, f32x4 c) {
    return __builtin_amdgcn_mfma_f32_16x16x32_bf16(a, b, c, 0, 0, 0);
}

// async global -> LDS, 16B per lane. LDS dest = wave-uniform base + lane*16.
static __device__ __forceinline__ void gload_lds16(const void* g, void* l) {
    __builtin_amdgcn_global_load_lds(
        (const __attribute__((address_space(1))) void*)g,
        (__attribute__((address_space(3))) void*)l, 16, 0, 0);
}

// ---------------------------------------------------------------------------
// mask -> bitmask (128 u32; bit k = key k masked). Storage encoding of the
// bool array is unknown (bool bytes / int32 / float32): detect deterministically.
// ---------------------------------------------------------------------------
__global__ void mask_bits_kernel(const u32* __restrict__ raw, u32* __restrict__ outbits) {
    __shared__ int okInt, okFloat;
    int t = threadIdx.x;
    if (t == 0) { okInt = 1; okFloat = 1; }
    __syncthreads();
    int li = 1, lf = 1;
    for (int i = t; i < 1024; i += blockDim.x) {
        u32 v = raw[i];
        if (v > 1u) li = 0;
        if (v != 0u && v != 0x3F800000u) lf = 0;
    }
    if (!li) atomicAnd(&okInt, 0);
    if (!lf) atomicAnd(&okFloat, 0);
    __syncthreads();
    const unsigned char* rb = (const unsigned char*)raw;
    if (t < (BDIM * SDIM) / 32) {
        u32 bits = 0;
        for (int j = 0; j < 32; ++j) {
            int i = t * 32 + j;
            int v;
            if (okInt)        v = (int)raw[i];
            else if (okFloat) v = (raw[i] != 0u) ? 1 : 0;
            else              v = (int)rb[i];
            bits |= (v ? 1u : 0u) << j;
        }
        outbits[t] = bits;
    }
}

// ---------------------------------------------------------------------------
// fp32 -> bf16 bulk conversion (8 elems/thread)
// ---------------------------------------------------------------------------
__global__ __launch_bounds__(256) void conv_f32_bf16(
    const float* __restrict__ s, u16* __restrict__ d, int n8)
{
    int i = blockIdx.x * 256 + threadIdx.x;
    if (i >= n8) return;
    float4 x0 = ((const float4*)s)[(size_t)i * 2];
    float4 x1 = ((const float4*)s)[(size_t)i * 2 + 1];
    uint4 o;
    o.x = (u32)f2b(x0.x) | ((u32)f2b(x0.y) << 16);
    o.y = (u32)f2b(x0.z) | ((u32)f2b(x0.w) << 16);
    o.z = (u32)f2b(x1.x) | ((u32)f2b(x1.y) << 16);
    o.w = (u32)f2b(x1.z) | ((u32)f2b(x1.w) << 16);
    ((uint4*)d)[i] = o;
}

// ---------------------------------------------------------------------------
// Fused QKV projection, R7-proven inner loop (64x64 tile, BK=32, 4 waves,
// manual coalesced uint4 staging into stride-56 LDS). N = 3*768 concatenated;
// blockIdx.y picks the matrix (block-uniform).
// Q -> bf16 [bh][s][d]; K -> fragment-major; V -> fragment-major.
// ---------------------------------------------------------------------------
__global__ __launch_bounds__(256) void gemm_qkv(
    const u16* __restrict__ A,
    const u16* __restrict__ wq, const u16* __restrict__ wk, const u16* __restrict__ wv,
    const float* __restrict__ bq, const float* __restrict__ bk, const float* __restrict__ bv,
    u16* __restrict__ qout, u16* __restrict__ kout, u16* __restrict__ vout)
{
    __shared__ u16 Al[64 * 56];
    __shared__ u16 Bl[64 * 56];
    int tid = threadIdx.x;
    int lane = tid & 63, w = tid >> 6;
    int r16 = lane & 15, g4 = lane >> 4;
    int wm = w >> 1, wn = w & 1;
    int mb = blockIdx.x * 64;
    int nbg = blockIdx.y * 64;
    int mid = nbg / EDIM;
    int nb = nbg - mid * EDIM;
    const u16* W = (mid == 0) ? wq : (mid == 1) ? wk : wv;
    const float* bias = (mid == 0) ? bq : (mid == 1) ? bk : bv;
    float scale = (mid == 0) ? SCALE_Q : 1.0f;

    f32x4 acc[2][2];
    acc[0][0] = zero4(); acc[0][1] = zero4(); acc[1][0] = zero4(); acc[1][1] = zero4();

    int srow = tid >> 2, scol = (tid & 3) * 8;

    for (int kb = 0; kb < EDIM; kb += 32) {
        __syncthreads();
        *(uint4*)&Al[srow * 56 + scol] =
            *(const uint4*)&A[(size_t)(mb + srow) * EDIM + kb + scol];
        *(uint4*)&Bl[srow * 56 + scol] =
            *(const uint4*)&W[(size_t)(nb + srow) * EDIM + kb + scol];
        __syncthreads();
        s16x8 a[2], bb[2];
        #pragma unroll
        for (int mi = 0; mi < 2; ++mi)
            a[mi] = *(const s16x8*)&Al[(wm * 32 + mi * 16 + r16) * 56 + g4 * 8];
        #pragma unroll
        for (int ni = 0; ni < 2; ++ni)
            bb[ni] = *(const s16x8*)&Bl[(wn * 32 + ni * 16 + r16) * 56 + g4 * 8];
        #pragma unroll
        for (int mi = 0; mi < 2; ++mi)
            #pragma unroll
            for (int ni = 0; ni < 2; ++ni)
                acc[mi][ni] = mfma16(a[mi], bb[ni], acc[mi][ni]);
    }

    #pragma unroll
    for (int mi = 0; mi < 2; ++mi) {
        #pragma unroll
        for (int ni = 0; ni < 2; ++ni) {
            int n = nb + wn * 32 + ni * 16 + r16;
            float bv_ = bias[n];
            #pragma unroll
            for (int r = 0; r < 4; ++r) {
                int m = mb + wm * 32 + mi * 16 + g4 * 4 + r;
                float c = (acc[mi][ni][r] + bv_) * scale;
                int s_ = m >> 1, b_ = m & 1, h_ = n >> 6, d_ = n & 63;
                if (mid == 0) {
                    qout[((size_t)(b_ * HDIM + h_) * SDIM + s_) * DDIM + d_] = f2b(c);
                } else if (mid == 1) {
                    size_t p = (size_t)(b_ * HDIM + h_) * HFRAG
                             + (size_t)(s_ >> 4) * 1024 + (size_t)((d_ >> 5) & 1) * 512
                             + (size_t)(((d_ >> 3) & 3) * 16 + (s_ & 15)) * 8 + (d_ & 7);
                    kout[p] = f2b(c);
                } else {
                    size_t p = (size_t)(b_ * HDIM + h_) * HFRAG
                             + (size_t)(s_ >> 5) * 2048 + (size_t)((d_ >> 4) & 3) * 512
                             + (size_t)(((s_ >> 3) & 3) * 16 + (d_ & 15)) * 8 + (s_ & 7);
                    vout[p] = f2b(c);
                }
            }
        }
    }
}

// ---------------------------------------------------------------------------
// Output projection: out = attn @ Wo^T + bo (fp32 row-major). R7 inner loop.
// ---------------------------------------------------------------------------
__global__ __launch_bounds__(256) void gemm_out(
    const u16* __restrict__ A, const u16* __restrict__ Wb,
    const float* __restrict__ bias, float* __restrict__ out_rm)
{
    __shared__ u16 Al[64 * 56];
    __shared__ u16 Bl[64 * 56];
    int tid = threadIdx.x;
    int lane = tid & 63, w = tid >> 6;
    int r16 = lane & 15, g4 = lane >> 4;
    int wm = w >> 1, wn = w & 1;
    int mb = blockIdx.x * 64, nb = blockIdx.y * 64;

    f32x4 acc[2][2];
    acc[0][0] = zero4(); acc[0][1] = zero4(); acc[1][0] = zero4(); acc[1][1] = zero4();

    int srow = tid >> 2, scol = (tid & 3) * 8;

    for (int kb = 0; kb < EDIM; kb += 32) {
        __syncthreads();
        *(uint4*)&Al[srow * 56 + scol] =
            *(const uint4*)&A[(size_t)(mb + srow) * EDIM + kb + scol];
        *(uint4*)&Bl[srow * 56 + scol] =
            *(const uint4*)&Wb[(size_t)(nb + srow) * EDIM + kb + scol];
        __syncthreads();
        s16x8 a[2], bb[2];
        #pragma unroll
        for (int mi = 0; mi < 2; ++mi)
            a[mi] = *(const s16x8*)&Al[(wm * 32 + mi * 16 + r16) * 56 + g4 * 8];
        #pragma unroll
        for (int ni = 0; ni < 2; ++ni)
            bb[ni] = *(const s16x8*)&Bl[(wn * 32 + ni * 16 + r16) * 56 + g4 * 8];
        #pragma unroll
        for (int mi = 0; mi < 2; ++mi)
            #pragma unroll
            for (int ni = 0; ni < 2; ++ni)
                acc[mi][ni] = mfma16(a[mi], bb[ni], acc[mi][ni]);
    }

    #pragma unroll
    for (int mi = 0; mi < 2; ++mi) {
        #pragma unroll
        for (int ni = 0; ni < 2; ++ni) {
            int n = nb + wn * 32 + ni * 16 + r16;
            float bv_ = bias[n];
            #pragma unroll
            for (int r = 0; r < 4; ++r) {
                int m = mb + wm * 32 + mi * 16 + g4 * 4 + r;
                out_rm[(size_t)m * EDIM + n] = acc[mi][ni][r] + bv_;
            }
        }
    }
}

// ---------------------------------------------------------------------------
// Fused flash attention — final (R12, measured best 223.0us):
// QBLK=32, split-K x2, XCD swizzle, 3-slot bias DMA ring (stage(t+2),
// vmcnt(17) counted — never drains), K/V fragment-major register prefetch
// depth-1 with mask word in-pipeline, swapped QK^T + in-lane softmax with
// defer-max (thr=4), cvt_pk P-pack + in-register shfl transpose.
// __launch_bounds__(128) (block-size only) is REQUIRED: omitting it or
// requesting min-waves>=4 forces hipcc to the 64-VGPR step -> massive spill.
// ---------------------------------------------------------------------------
struct KV { s16x8 k0, k1, k2, k3, v0, v1, v2, v3; u32 mw; };

__global__ __launch_bounds__(128) void attn_fused(
    const u16* __restrict__ qw, const u16* __restrict__ kf_g,
    const u16* __restrict__ vf_g, const float* __restrict__ bias,
    const u32* __restrict__ maskBits, u16* __restrict__ attn_out)
{
    __shared__ __align__(1024) unsigned char SM[24576];
    // per wave 12288B: bias ring 3 x 4KB ([32 q][32 k] floats, quad-XOR swizzled)
    // epilogue reuse: As[64][68] f32 (17408B) + Ml/Ll (512B).

    // XCD swizzle: flat%8 = XCD -> contiguous 192-block chunk (3 heads) per XCD
    int flat = blockIdx.y * 64 + blockIdx.x;
    int virt = (flat & 7) * 192 + (flat >> 3);
    int qt = virt & 63, bh = virt >> 6;

    int tid = threadIdx.x;
    int w = tid >> 6, lane = tid & 63;
    int r16 = lane & 15, g4 = lane >> 4;
    int ga = g4 >> 1, gb = g4 & 1;           // for the P shuffle
    int qbase = qt * 32;
    int b_ = bh / HDIM, h_ = bh % HDIM;
    const u16* Q  = qw   + (size_t)bh * SDIM * DDIM;
    const u16* KF = kf_g + (size_t)bh * HFRAG;
    const u16* VF = vf_g + (size_t)bh * HFRAG;
    const float* BrowQ = bias + (size_t)bh * SDIM * SDIM + (size_t)qbase * SDIM;
    const u32* mB = maskBits + b_ * (SDIM / 32);

    unsigned char* wb = SM + w * 12288;
    float* RingW = (float*)wb;               // 3 slots x 1024 floats

    // P-shuffle source lanes (per target lane)
    int srcLo = (2 * gb) * 16 + r16;         // for words 0,1
    int srcHi = (2 * gb + 1) * 16 + r16;     // for words 2,3

    s16x8 qf[2][2];
    #pragma unroll
    for (int h = 0; h < 2; ++h) {
        qf[h][0] = *(const s16x8*)&Q[(size_t)(qbase + 16 * h + r16) * DDIM + g4 * 8];
        qf[h][1] = *(const s16x8*)&Q[(size_t)(qbase + 16 * h + r16) * DDIM + g4 * 8 + 32];
    }

    f32x4 accO[2][4];
    #pragma unroll
    for (int h = 0; h < 2; ++h)
        #pragma unroll
        for (int dt = 0; dt < 4; ++dt) accO[h][dt] = zero4();
    float m_run[2] = {-1e30f, -1e30f}, l_run[2] = {0.f, 0.f};  // column q=r16 (+16h)

    const int k0 = w * KSPLIT;

    auto issue_kv = [&](int t, KV& dst) {
        int tc = t < NIT ? t : NIT - 1;              // clamped (uniform vm count)
        int kbn = k0 + tc * 32;
        const u16* KT = KF + (size_t)(kbn >> 4) * 1024;
        dst.k0 = *(const s16x8*)&KT[lane * 8];
        dst.k1 = *(const s16x8*)&KT[512 + lane * 8];
        dst.k2 = *(const s16x8*)&KT[1024 + lane * 8];
        dst.k3 = *(const s16x8*)&KT[1536 + lane * 8];
        const u16* VT = VF + (size_t)(kbn >> 5) * 2048;
        dst.v0 = *(const s16x8*)&VT[lane * 8];
        dst.v1 = *(const s16x8*)&VT[512 + lane * 8];
        dst.v2 = *(const s16x8*)&VT[1024 + lane * 8];
        dst.v3 = *(const s16x8*)&VT[1536 + lane * 8];
        dst.mw = mB[kbn >> 5];                       // broadcast line, in-pipeline
    };

    // stage bias tile t into ring slot t%3; 4 DMA of 1KB, each 8 rows x 128B;
    // source quad XOR-permuted per row (involution).
    auto stage_bias = [&](int t) {
        int tc = t < NIT ? t : NIT - 1;              // clamped (uniform vm count)
        int kb = k0 + tc * 32;
        unsigned char* slot = wb + (tc % 3) * 4096;
        int sq = (lane & 7) ^ ((lane >> 3) & 7);
        #pragma unroll
        for (int j = 0; j < 4; ++j) {
            int row = j * 8 + (lane >> 3);
            gload_lds16(&BrowQ[(size_t)row * SDIM + kb + sq * 4], slot + j * 1024);
        }
    };

    auto compute = [&](int t, KV& cur) {
        u32 mw = cur.mw;
        const float* Bs = RingW + (t % 3) * 1024;
        // QK^T swapped, both halves: sc[h][kt][r] = S[k=16kt+4g4+r][q=16h+r16]
        f32x4 sc[2][2];
        #pragma unroll
        for (int h = 0; h < 2; ++h) {
            sc[h][0] = mfma16(cur.k1, qf[h][1], mfma16(cur.k0, qf[h][0], zero4()));
            sc[h][1] = mfma16(cur.k3, qf[h][1], mfma16(cur.k2, qf[h][0], zero4()));
        }
        // bias + mask poison
        #pragma unroll
        for (int h = 0; h < 2; ++h) {
            int rr = 16 * h + r16;
            #pragma unroll
            for (int kt = 0; kt < 2; ++kt) {
                float4 bc = *(const float4*)&Bs[rr * 32 + (((4 * kt + g4) ^ (r16 & 7)) * 4)];
                u32 mseg = (mw >> (16 * kt + 4 * g4)) & 0xF;
                sc[h][kt][0] = (mseg & 1) ? -1e30f : sc[h][kt][0] + bc.x;
                sc[h][kt][1] = (mseg & 2) ? -1e30f : sc[h][kt][1] + bc.y;
                sc[h][kt][2] = (mseg & 4) ? -1e30f : sc[h][kt][2] + bc.z;
                sc[h][kt][3] = (mseg & 8) ? -1e30f : sc[h][kt][3] + bc.w;
            }
        }
        // per half: online softmax (column q = 16h+r16, defer-max thr=4),
        // then P pack + in-register transpose to PV A-fragments, then PV.
        #pragma unroll
        for (int h = 0; h < 2; ++h) {
            float pm = fmaxf(
                fmaxf(fmaxf(sc[h][0][0], sc[h][0][1]), fmaxf(sc[h][0][2], sc[h][0][3])),
                fmaxf(fmaxf(sc[h][1][0], sc[h][1][1]), fmaxf(sc[h][1][2], sc[h][1][3])));
            pm = fmaxf(pm, __shfl_xor(pm, 16));
            pm = fmaxf(pm, __shfl_xor(pm, 32));
            bool norescale = __all(pm <= m_run[h] + 4.f);
            float mn = norescale ? m_run[h] : fmaxf(m_run[h], pm);
            float p[8];
            #pragma unroll
            for (int kt = 0; kt < 2; ++kt)
                #pragma unroll
                for (int r = 0; r < 4; ++r)
                    p[kt * 4 + r] = __expf(sc[h][kt][r] - mn);
            float ps = ((p[0] + p[1]) + (p[2] + p[3])) + ((p[4] + p[5]) + (p[6] + p[7]));
            ps += __shfl_xor(ps, 16);
            ps += __shfl_xor(ps, 32);
            if (norescale) {
                l_run[h] += ps;
            } else {
                float alpha = __expf(m_run[h] - mn);
                l_run[h] = l_run[h] * alpha + ps;
                m_run[h] = mn;
                float aR0 = __shfl(alpha, g4 * 4 + 0);
                float aR1 = __shfl(alpha, g4 * 4 + 1);
                float aR2 = __shfl(alpha, g4 * 4 + 2);
                float aR3 = __shfl(alpha, g4 * 4 + 3);
                #pragma unroll
                for (int dt = 0; dt < 4; ++dt) {
                    accO[h][dt][0] *= aR0;
                    accO[h][dt][1] *= aR1;
                    accO[h][dt][2] *= aR2;
                    accO[h][dt][3] *= aR3;
                }
            }
            // pack column-form P; word m covers k = 16(m>>1)+4g4+2(m&1)+{0,1}
            u32 W0 = cvt_pk_bf16(p[0], p[1]);
            u32 W1 = cvt_pk_bf16(p[2], p[3]);
            u32 W2 = cvt_pk_bf16(p[4], p[5]);
            u32 W3 = cvt_pk_bf16(p[6], p[7]);
            // transpose: target word w <- src lane (w<2 ? srcLo : srcHi),
            // src word (2a + (w&1)); select by a = g4>>1
            u32 o0A = (u32)__shfl((int)W0, srcLo), o0B = (u32)__shfl((int)W2, srcLo);
            u32 o1A = (u32)__shfl((int)W1, srcLo), o1B = (u32)__shfl((int)W3, srcLo);
            u32 o2A = (u32)__shfl((int)W0, srcHi), o2B = (u32)__shfl((int)W2, srcHi);
            u32 o3A = (u32)__shfl((int)W1, srcHi), o3B = (u32)__shfl((int)W3, srcHi);
            uint4 pw;
            pw.x = ga ? o0B : o0A;
            pw.y = ga ? o1B : o1A;
            pw.z = ga ? o2B : o2A;
            pw.w = ga ? o3B : o3A;
            s16x8 pf = __builtin_bit_cast(s16x8, pw);
            // PV for this half
            accO[h][0] = mfma16(pf, cur.v0, accO[h][0]);
            accO[h][1] = mfma16(pf, cur.v1, accO[h][1]);
            accO[h][2] = mfma16(pf, cur.v2, accO[h][2]);
            accO[h][3] = mfma16(pf, cur.v3, accO[h][3]);
        }
    };

    // prologue: kv(0) + bias tiles 0,1 staged (depth-2)
    KV A, B;
    issue_kv(0, A);
    stage_bias(0);
    stage_bias(1);

    for (int t = 0; t < NIT; t += 2) {
        issue_kv(t + 1, B);
        stage_bias(t + 2);
        asm volatile("s_waitcnt vmcnt(17)" ::: "memory");
        __builtin_amdgcn_sched_barrier(0);
        compute(t, A);

        issue_kv(t + 2, A);
        stage_bias(t + 3);
        asm volatile("s_waitcnt vmcnt(17)" ::: "memory");
        __builtin_amdgcn_sched_barrier(0);
        compute(t + 1, B);
    }

    // ---- combine the two waves' partials (reuse LDS) ----
    __syncthreads();
    float* As = (float*)SM;                 // [64][68]
    float* Ml = (float*)(SM + 17408);       // [64]
    float* Ll = Ml + 64;
    #pragma unroll
    for (int h = 0; h < 2; ++h)
        #pragma unroll
        for (int dt = 0; dt < 4; ++dt)
            #pragma unroll
            for (int r = 0; r < 4; ++r)
                As[(size_t)(w * 32 + 16 * h + g4 * 4 + r) * 68 + dt * 16 + r16] = accO[h][dt][r];
    if (g4 == 0) {
        #pragma unroll
        for (int h = 0; h < 2; ++h) {
            Ml[w * 32 + 16 * h + r16] = m_run[h];
            Ll[w * 32 + 16 * h + r16] = l_run[h];
        }
    }
    __syncthreads();

    #pragma unroll
    for (int h = 0; h < 2; ++h) {
        #pragma unroll
        for (int dg = 0; dg < 2; ++dg) {
            int d = w * 32 + dg * 16 + r16;
            #pragma unroll
            for (int r = 0; r < 4; ++r) {
                int q = 16 * h + g4 * 4 + r;
                float m0 = Ml[q], m1 = Ml[32 + q];
                float mt = fmaxf(m0, m1);
                float e0 = __expf(m0 - mt), e1 = __expf(m1 - mt);
                float lt = Ll[q] * e0 + Ll[32 + q] * e1;
                float o = (As[(size_t)q * 68 + d] * e0 + As[(size_t)(32 + q) * 68 + d] * e1) / lt;
                attn_out[((size_t)(qbase + q) * BDIM + b_) * EDIM + h_ * DDIM + d] = f2b(o);
            }
        }
    }
}

extern "C" void kernel_launch(void* const* d_in, const int* in_sizes, int n_in,
                              void* d_out, int out_size, void* d_ws, size_t ws_size,
                              hipStream_t stream) {
    const float* query     = (const float*)d_in[0];
    const float* attn_bias = (const float*)d_in[1];
    const u32*   mask_raw  = (const u32*)d_in[2];
    const float* Wq = (const float*)d_in[3];
    const float* bq = (const float*)d_in[4];
    const float* Wk = (const float*)d_in[5];
    const float* bk = (const float*)d_in[6];
    const float* Wv = (const float*)d_in[7];
    const float* bv = (const float*)d_in[8];
    const float* Wo = (const float*)d_in[9];
    const float* bo = (const float*)d_in[10];
    float* out = (float*)d_out;

    // workspace layout: maskBits(16KB) | qws | kws | vws | aws(=qbf) | 4x Wbf
    char* ws = (char*)d_ws;
    u32* maskB = (u32*)ws;
    const size_t HEADSZ = (size_t)BDIM * HDIM * SDIM * DDIM;  // 3,145,728 elems
    const size_t WSZ = (size_t)EDIM * EDIM;                   //   589,824 elems
    u16* qws = (u16*)(ws + 16384);
    u16* kws = qws + HEADSZ;
    u16* vws = kws + HEADSZ;
    u16* aws = vws + HEADSZ;      // attn out; doubles as bf16 query (qbf)
    u16* qbf = aws;
    u16* wWq = aws + HEADSZ;
    u16* wWk = wWq + WSZ;
    u16* wWv = wWk + WSZ;
    u16* wWo = wWv + WSZ;

    mask_bits_kernel<<<1, 256, 0, stream>>>(mask_raw, maskB);

    conv_f32_bf16<<<(int)(MDIM * EDIM / 8 / 256), 256, 0, stream>>>(query, qbf, MDIM * EDIM / 8);
    conv_f32_bf16<<<(int)(WSZ / 8 / 256), 256, 0, stream>>>(Wq, wWq, (int)(WSZ / 8));
    conv_f32_bf16<<<(int)(WSZ / 8 / 256), 256, 0, stream>>>(Wk, wWk, (int)(WSZ / 8));
    conv_f32_bf16<<<(int)(WSZ / 8 / 256), 256, 0, stream>>>(Wv, wWv, (int)(WSZ / 8));
    conv_f32_bf16<<<(int)(WSZ / 8 / 256), 256, 0, stream>>>(Wo, wWo, (int)(WSZ / 8));

    dim3 gq(MDIM / 64, (3 * EDIM) / 64);
    gemm_qkv<<<gq, 256, 0, stream>>>(qbf, wWq, wWk, wWv, bq, bk, bv, qws, kws, vws);

    dim3 ga(64, BDIM * HDIM);
    attn_fused<<<ga, 128, 0, stream>>>(qws, kws, vws, attn_bias, maskB, aws);

    dim3 go(MDIM / 64, EDIM / 64);
    gemm_out<<<go, 256, 0, stream>>>(aws, wWo, bo, out);
}